// Round 5
// baseline (292.916 us; speedup 1.0000x reference)
//
#include <hip/hip_runtime.h>
#include <cstddef>

// Problem shape (fixed): N=50000, K=16, C_IN=128, C2=256, C_OUT=128.
#define C_IN  128
#define C2    256
#define C_OUT 128
#define KNBR  16

typedef unsigned short u16;
typedef __attribute__((ext_vector_type(8))) short bf16x8;   // 8 bf16 (4 VGPRs)
typedef __attribute__((ext_vector_type(4))) float f32x4;

__device__ __forceinline__ float bf2f(u16 h) {
    return __uint_as_float(((unsigned int)h) << 16);
}
__device__ __forceinline__ u16 f2bf(float x) {
    unsigned int u = __float_as_uint(x);
    return (u16)((u + 0x7fffu + ((u >> 16) & 1u)) >> 16);
}

// Transpose + convert weights to bf16, n-major [N][K]:
// W1 [128][256] -> W1t [256][128]; Ws [256][256] -> Wst [256][256];
// Wm [256][128] -> Wmt [128][256].
__global__ void prep_k(const float* __restrict__ W1, const float* __restrict__ Ws,
                       const float* __restrict__ Wm, u16* __restrict__ W1t,
                       u16* __restrict__ Wst, u16* __restrict__ Wmt)
{
    const int n = blockIdx.x, t = threadIdx.x;
    if (blockIdx.y == 0) {
        if (t < 128) W1t[n * 128 + t] = f2bf(W1[t * 256 + n]);
    } else if (blockIdx.y == 1) {
        Wst[n * 256 + t] = f2bf(Ws[t * 256 + n]);
    } else {
        if (n < 128) Wmt[n * 256 + t] = f2bf(Wm[t * 128 + n]);
    }
}

// MFMA bf16 GEMM, 128x128 tile, BK=64, 4 waves, 4x4 16x16x32 frags/wave.
// A row-major: fp32 (convert on stage) or bf16, stride lda.
// Bt: n-major bf16 [Nc][Kd].
// packed row layout (per point, 512 u16 = 64 groups of 16B):
//   group g: [ey[4g..4g+3] bf16 | x[4g..4g+3] bf16]
// MODE 1: BN(relu(z+bias)) -> x slots of packed + contiguous bf16 xbn_c.
// MODE 0: exp(z) -> ey slots of packed.
// MODE 2: z + bias -> fp32 Cf.
template<int MODE, bool A_BF16>
__global__ __launch_bounds__(256)
void mfma_gemm(const void* __restrict__ Ap, int lda,
               const u16* __restrict__ Bt,
               const float* __restrict__ bias, const float* __restrict__ gamma,
               const float* __restrict__ beta, const float* __restrict__ mean,
               const float* __restrict__ var,
               float* __restrict__ Cf, u16* __restrict__ packed,
               u16* __restrict__ xbn_c, int M, int Kd, int Nc)
{
    __shared__ u16 As[128][72];   // 64 + 8 pad (16B-aligned rows, 2-way alias ok)
    __shared__ u16 Bs[128][72];
    const int tid = threadIdx.x;
    const int w = tid >> 6, l = tid & 63, q = l >> 4, r = l & 15;
    const int wm = w & 1, wn = w >> 1;
    const int m0 = blockIdx.x * 128, n0 = blockIdx.y * 128;

    f32x4 acc[4][4] = {};

    for (int k0 = 0; k0 < Kd; k0 += 64) {
        if (A_BF16) {
            const u16* A = (const u16*)Ap;
            #pragma unroll
            for (int i = 0; i < 4; i++) {
                int idx = tid + i * 256;
                int row = idx >> 3, g = (idx & 7) * 8;
                int gm = m0 + row;
                uint4 v = make_uint4(0u, 0u, 0u, 0u);
                if (gm < M)
                    v = *(const uint4*)(A + (size_t)gm * lda + k0 + g);
                *(uint4*)&As[row][g] = v;
            }
        } else {
            const float* A = (const float*)Ap;
            #pragma unroll
            for (int i = 0; i < 8; i++) {
                int idx = tid + i * 256;
                int row = idx >> 4, g = (idx & 15) * 4;
                int gm = m0 + row;
                float4 v = make_float4(0.f, 0.f, 0.f, 0.f);
                if (gm < M)
                    v = *(const float4*)(A + (size_t)gm * lda + k0 + g);
                ushort4 h;
                h.x = f2bf(v.x); h.y = f2bf(v.y);
                h.z = f2bf(v.z); h.w = f2bf(v.w);
                *(ushort4*)&As[row][g] = h;
            }
        }
        #pragma unroll
        for (int i = 0; i < 4; i++) {
            int idx = tid + i * 256;
            int row = idx >> 3, g = (idx & 7) * 8;
            *(uint4*)&Bs[row][g] =
                *(const uint4*)(Bt + (size_t)(n0 + row) * Kd + k0 + g);
        }
        __syncthreads();

        #pragma unroll
        for (int h = 0; h < 2; h++) {
            bf16x8 af[4], bfr[4];
            #pragma unroll
            for (int i = 0; i < 4; i++)
                af[i] = *(const bf16x8*)&As[wm * 64 + i * 16 + r][h * 32 + q * 8];
            #pragma unroll
            for (int j = 0; j < 4; j++)
                bfr[j] = *(const bf16x8*)&Bs[wn * 64 + j * 16 + r][h * 32 + q * 8];
            #pragma unroll
            for (int i = 0; i < 4; i++)
                #pragma unroll
                for (int j = 0; j < 4; j++)
                    acc[i][j] = __builtin_amdgcn_mfma_f32_16x16x32_bf16(
                        af[i], bfr[j], acc[i][j], 0, 0, 0);
        }
        __syncthreads();
    }

    // epilogue: lane (q,r), reg p -> row m0+wm*64+i*16+q*4+p, col n0+wn*64+j*16+r
    #pragma unroll
    for (int j = 0; j < 4; j++) {
        const int ch = n0 + wn * 64 + j * 16 + r;
        float bi = 0.f, be = 0.f, mu = 0.f, iv = 0.f, bo = 0.f;
        if (MODE == 1) {
            bi = bias[ch]; be = beta[ch]; mu = mean[ch];
            iv = gamma[ch] * rsqrtf(var[ch] + 1e-5f);
        }
        if (MODE == 2) bo = bias[ch];
        const int goff = (ch >> 2) * 8 + (ch & 3);   // interleaved group offset
        #pragma unroll
        for (int i = 0; i < 4; i++) {
            const int mb = m0 + wm * 64 + i * 16 + q * 4;
            #pragma unroll
            for (int p = 0; p < 4; p++) {
                const int m = mb + p;
                if (m >= M) continue;
                float x = acc[i][j][p];
                if (MODE == 1) {
                    x = fmaxf(x + bi, 0.f);
                    x = (x - mu) * iv + be;
                    u16 hx = f2bf(x);
                    packed[(size_t)m * 512 + goff + 4] = hx;
                    xbn_c[(size_t)m * 256 + ch] = hx;
                } else if (MODE == 0) {
                    packed[(size_t)m * 512 + goff] = f2bf(__expf(x));
                } else {
                    Cf[(size_t)m * Nc + ch] = x + bo;
                }
            }
        }
    }
}

// One wave per point: 16 neighbors, ONE uint4 (16B) load per neighbor per
// lane (wave load = exactly one 1KB packed row, fully coalesced). ey is
// precomputed exp(y); softmax-pool needs only unpack+fma. Writes bf16 feat.
__global__ __launch_bounds__(256)
void gather_k(const u16* __restrict__ packed, const int* __restrict__ nidx,
              u16* __restrict__ featb, int N)
{
    __shared__ int rows[4 * KNBR];
    const int tid = threadIdx.x;
    const int p0 = blockIdx.x * 4;

    if (tid < 4 * KNBR) {
        int n = p0 + (tid >> 4);
        rows[tid] = (n < N) ? nidx[n * KNBR + (tid & 15)] : 0;
    }
    __syncthreads();

    const int w = tid >> 6;       // wave id 0..3 -> point p0+w
    const int l = tid & 63;       // group l: channels 4l..4l+3
    const int p = p0 + w;
    if (p >= N) return;

    uint4 v[KNBR];
    #pragma unroll
    for (int k = 0; k < KNBR; k++)
        v[k] = *(const uint4*)(packed + (size_t)rows[w * KNBR + k] * 512 + l * 8);

    float d0 = 0.f, d1 = 0.f, d2 = 0.f, d3 = 0.f;
    float u0 = 0.f, u1 = 0.f, u2 = 0.f, u3 = 0.f;
    #pragma unroll
    for (int k = 0; k < KNBR; k++) {
        float e0 = __uint_as_float(v[k].x << 16);
        float e1 = __uint_as_float(v[k].x & 0xffff0000u);
        float e2 = __uint_as_float(v[k].y << 16);
        float e3 = __uint_as_float(v[k].y & 0xffff0000u);
        float x0 = __uint_as_float(v[k].z << 16);
        float x1 = __uint_as_float(v[k].z & 0xffff0000u);
        float x2 = __uint_as_float(v[k].w << 16);
        float x3 = __uint_as_float(v[k].w & 0xffff0000u);
        d0 += e0; d1 += e1; d2 += e2; d3 += e3;
        u0 = fmaf(e0, x0, u0);
        u1 = fmaf(e1, x1, u1);
        u2 = fmaf(e2, x2, u2);
        u3 = fmaf(e3, x3, u3);
    }
    ushort4 o;
    o.x = f2bf(u0 / d0); o.y = f2bf(u1 / d1);
    o.z = f2bf(u2 / d2); o.w = f2bf(u3 / d3);
    *(ushort4*)(featb + (size_t)p * C2 + l * 4) = o;
}

extern "C" void kernel_launch(void* const* d_in, const int* in_sizes, int n_in,
                              void* d_out, int out_size, void* d_ws, size_t ws_size,
                              hipStream_t stream)
{
    const float* features = (const float*)d_in[0];
    const int*   nidx     = (const int*)d_in[1];
    const float* W1       = (const float*)d_in[2];
    const float* b1       = (const float*)d_in[3];
    const float* gamma    = (const float*)d_in[4];
    const float* beta     = (const float*)d_in[5];
    const float* mean     = (const float*)d_in[6];
    const float* var      = (const float*)d_in[7];
    const float* Ws       = (const float*)d_in[8];
    const float* Wm       = (const float*)d_in[9];
    const float* bm       = (const float*)d_in[10];
    float* out = (float*)d_out;

    const int N = in_sizes[0] / C_IN;   // 50000

    u16* packed = (u16*)d_ws;                      // N x 512 interleaved [ey|x]
    u16* xbn_c  = packed + (size_t)N * 512;        // N x 256 contiguous bf16 x
    u16* W1t    = xbn_c + (size_t)N * 256;         // 256 x 128
    u16* Wst    = W1t + 256 * 128;                 // 256 x 256
    u16* Wmt    = Wst + 256 * 256;                 // 128 x 256
    // feat lives in d_out (bf16 N x 256 == 25.6 MB == out buffer exactly).
    // Safe: K3b blocks read all their A rows before the epilogue overwrites
    // the same rows, and no block touches another block's rows.
    u16* featb = (u16*)d_out;

    // P0: weights -> bf16, n-major
    prep_k<<<dim3(256, 3), 256, 0, stream>>>(W1, Ws, Wm, W1t, Wst, Wmt);

    const int MT = (N + 127) / 128;   // 391

    // K1: x = BN(relu(features @ W1 + b1)) -> packed x-slots + xbn_c
    mfma_gemm<1, false><<<dim3(MT, 2), 256, 0, stream>>>(
        features, C_IN, W1t, b1, gamma, beta, mean, var,
        nullptr, packed, xbn_c, N, C_IN, C2);
    // K2: ey = exp(xbn_c @ Ws) -> packed ey-slots
    mfma_gemm<0, true><<<dim3(MT, 2), 256, 0, stream>>>(
        xbn_c, C2, Wst, nullptr, nullptr, nullptr, nullptr, nullptr,
        nullptr, packed, nullptr, N, C2, C2);
    // K3a: gather + softmax-pool -> featb (aliases d_out)
    gather_k<<<(N + 3) / 4, 256, 0, stream>>>(packed, nidx, featb, N);
    // K3b: out = featb @ Wm + bm
    mfma_gemm<2, true><<<dim3(MT, 1), 256, 0, stream>>>(
        featb, C2, Wmt, bm, nullptr, nullptr, nullptr, nullptr,
        out, nullptr, nullptr, N, C2, C_OUT);
}

// Round 6
// 268.154 us; speedup vs baseline: 1.0923x; 1.0923x over previous
//
#include <hip/hip_runtime.h>
#include <cstddef>

// Problem shape (fixed): N=50000, K=16, C_IN=128, C2=256, C_OUT=128.
#define C_IN  128
#define C2    256
#define C_OUT 128
#define KNBR  16

typedef unsigned short u16;
typedef __attribute__((ext_vector_type(8))) short bf16x8;   // 8 bf16 (4 VGPRs)
typedef __attribute__((ext_vector_type(4))) float f32x4;

__device__ __forceinline__ float bf2f(u16 h) {
    return __uint_as_float(((unsigned int)h) << 16);
}
__device__ __forceinline__ u16 f2bf(float x) {
    unsigned int u = __float_as_uint(x);
    return (u16)((u + 0x7fffu + ((u >> 16) & 1u)) >> 16);
}

// Transpose + convert weights to bf16, n-major [N][K]:
// W1 [128][256] -> W1t [256][128]; Ws [256][256] -> Wst [256][256];
// Wm [256][128] -> Wmt [128][256].
__global__ void prep_k(const float* __restrict__ W1, const float* __restrict__ Ws,
                       const float* __restrict__ Wm, u16* __restrict__ W1t,
                       u16* __restrict__ Wst, u16* __restrict__ Wmt)
{
    const int n = blockIdx.x, t = threadIdx.x;
    if (blockIdx.y == 0) {
        if (t < 128) W1t[n * 128 + t] = f2bf(W1[t * 256 + n]);
    } else if (blockIdx.y == 1) {
        Wst[n * 256 + t] = f2bf(Ws[t * 256 + n]);
    } else {
        if (n < 128) Wmt[n * 256 + t] = f2bf(Wm[t * 128 + n]);
    }
}

// Fused MLP: per 128-point block,
//   x  = BN(relu(features @ W1 + b1))   (GEMM1, K=128; x -> LDS xs + packed)
//   ey = exp(x @ Ws)                    (GEMM2, K=256, A from LDS; -> packed)
// packed row (512 u16): [ey[0..255] | x[0..255]], both bf16.
__global__ __launch_bounds__(256)
void mlp_k(const float* __restrict__ F, const u16* __restrict__ W1t,
           const u16* __restrict__ Wst,
           const float* __restrict__ bias, const float* __restrict__ gamma,
           const float* __restrict__ beta, const float* __restrict__ mean,
           const float* __restrict__ var,
           u16* __restrict__ packed, int N)
{
    __shared__ u16 As[128][136];   // features tile, full K=128 (+8 pad)
    __shared__ u16 Bs[128][72];    // weight staging, 128 n x 64 k (+8 pad)
    __shared__ u16 xs[128][264];   // x tile, full K=256 (+8 pad)

    const int tid = threadIdx.x;
    const int w = tid >> 6, l = tid & 63, q = l >> 4, r = l & 15;
    const int wm = w & 1, wn = w >> 1;
    const int m0 = blockIdx.x * 128;

    // stage As: 128x128 fp32 -> bf16 (4096 float4, 16/thread)
    #pragma unroll
    for (int i = 0; i < 16; i++) {
        int idx = tid + i * 256;
        int row = idx >> 5, c4 = (idx & 31) * 4;
        int gm = m0 + row;
        float4 v = make_float4(0.f, 0.f, 0.f, 0.f);
        if (gm < N) v = *(const float4*)(F + (size_t)gm * C_IN + c4);
        ushort4 h;
        h.x = f2bf(v.x); h.y = f2bf(v.y); h.z = f2bf(v.z); h.w = f2bf(v.w);
        *(ushort4*)&As[row][c4] = h;
    }

    // ---- GEMM1: x = F @ W1, output 128 x 256 in two 128-col halves ----
    #pragma unroll 1
    for (int nh = 0; nh < 2; nh++) {
        f32x4 acc[4][4] = {};
        #pragma unroll 1
        for (int k0 = 0; k0 < C_IN; k0 += 64) {
            __syncthreads();   // prior Bs readers done (also covers As stage)
            #pragma unroll
            for (int i = 0; i < 4; i++) {
                int idx = tid + i * 256;
                int row = idx >> 3, g = (idx & 7) * 8;
                *(uint4*)&Bs[row][g] = *(const uint4*)(
                    W1t + (size_t)(nh * 128 + row) * C_IN + k0 + g);
            }
            __syncthreads();
            #pragma unroll
            for (int h = 0; h < 2; h++) {
                bf16x8 af[4], bfr[4];
                #pragma unroll
                for (int i = 0; i < 4; i++)
                    af[i] = *(const bf16x8*)&As[wm * 64 + i * 16 + r][k0 + h * 32 + q * 8];
                #pragma unroll
                for (int j = 0; j < 4; j++)
                    bfr[j] = *(const bf16x8*)&Bs[wn * 64 + j * 16 + r][h * 32 + q * 8];
                #pragma unroll
                for (int i = 0; i < 4; i++)
                    #pragma unroll
                    for (int j = 0; j < 4; j++)
                        acc[i][j] = __builtin_amdgcn_mfma_f32_16x16x32_bf16(
                            af[i], bfr[j], acc[i][j], 0, 0, 0);
            }
        }
        // epilogue 1: BN(relu(z+bias)) -> xs + packed x-half
        #pragma unroll
        for (int j = 0; j < 4; j++) {
            const int ch = nh * 128 + wn * 64 + j * 16 + r;
            const float bi = bias[ch], be = beta[ch], mu = mean[ch];
            const float iv = gamma[ch] * rsqrtf(var[ch] + 1e-5f);
            #pragma unroll
            for (int i = 0; i < 4; i++) {
                const int mb = wm * 64 + i * 16 + q * 4;
                #pragma unroll
                for (int p = 0; p < 4; p++) {
                    const int ml = mb + p;
                    float x = fmaxf(acc[i][j][p] + bi, 0.f);
                    x = (x - mu) * iv + be;
                    u16 hx = f2bf(x);
                    xs[ml][ch] = hx;
                    if (m0 + ml < N)
                        packed[(size_t)(m0 + ml) * 512 + 256 + ch] = hx;
                }
            }
        }
    }

    // ---- GEMM2: ey = exp(x @ Ws), A from xs, two 128-col halves ----
    #pragma unroll 1
    for (int nh = 0; nh < 2; nh++) {
        f32x4 acc[4][4] = {};
        #pragma unroll 1
        for (int k0 = 0; k0 < C2; k0 += 64) {
            __syncthreads();   // prior Bs readers / xs writers done
            #pragma unroll
            for (int i = 0; i < 4; i++) {
                int idx = tid + i * 256;
                int row = idx >> 3, g = (idx & 7) * 8;
                *(uint4*)&Bs[row][g] = *(const uint4*)(
                    Wst + (size_t)(nh * 128 + row) * C2 + k0 + g);
            }
            __syncthreads();
            #pragma unroll
            for (int h = 0; h < 2; h++) {
                bf16x8 af[4], bfr[4];
                #pragma unroll
                for (int i = 0; i < 4; i++)
                    af[i] = *(const bf16x8*)&xs[wm * 64 + i * 16 + r][k0 + h * 32 + q * 8];
                #pragma unroll
                for (int j = 0; j < 4; j++)
                    bfr[j] = *(const bf16x8*)&Bs[wn * 64 + j * 16 + r][h * 32 + q * 8];
                #pragma unroll
                for (int i = 0; i < 4; i++)
                    #pragma unroll
                    for (int j = 0; j < 4; j++)
                        acc[i][j] = __builtin_amdgcn_mfma_f32_16x16x32_bf16(
                            af[i], bfr[j], acc[i][j], 0, 0, 0);
            }
        }
        // epilogue 2: exp -> packed ey-half
        #pragma unroll
        for (int j = 0; j < 4; j++) {
            const int ch = nh * 128 + wn * 64 + j * 16 + r;
            #pragma unroll
            for (int i = 0; i < 4; i++) {
                const int mb = wm * 64 + i * 16 + q * 4;
                #pragma unroll
                for (int p = 0; p < 4; p++) {
                    const int ml = mb + p;
                    if (m0 + ml < N)
                        packed[(size_t)(m0 + ml) * 512 + ch] =
                            f2bf(__expf(acc[i][j][p]));
                }
            }
        }
    }
}

// Output GEMM: out = featb @ Wm + bm.  A bf16 row-major, Bt n-major bf16.
__global__ __launch_bounds__(256)
void out_gemm(const u16* __restrict__ A, const u16* __restrict__ Bt,
              const float* __restrict__ bias, float* __restrict__ Cf, int N)
{
    __shared__ u16 As[128][72];
    __shared__ u16 Bs[128][72];
    const int tid = threadIdx.x;
    const int w = tid >> 6, l = tid & 63, q = l >> 4, r = l & 15;
    const int wm = w & 1, wn = w >> 1;
    const int m0 = blockIdx.x * 128;

    f32x4 acc[4][4] = {};

    #pragma unroll 1
    for (int k0 = 0; k0 < C2; k0 += 64) {
        #pragma unroll
        for (int i = 0; i < 4; i++) {
            int idx = tid + i * 256;
            int row = idx >> 3, g = (idx & 7) * 8;
            int gm = m0 + row;
            uint4 v = make_uint4(0u, 0u, 0u, 0u);
            if (gm < N) v = *(const uint4*)(A + (size_t)gm * C2 + k0 + g);
            *(uint4*)&As[row][g] = v;
            *(uint4*)&Bs[row][g] = *(const uint4*)(
                Bt + (size_t)row * C2 + k0 + g);   // Wmt is 128 x 256
        }
        __syncthreads();
        #pragma unroll
        for (int h = 0; h < 2; h++) {
            bf16x8 af[4], bfr[4];
            #pragma unroll
            for (int i = 0; i < 4; i++)
                af[i] = *(const bf16x8*)&As[wm * 64 + i * 16 + r][h * 32 + q * 8];
            #pragma unroll
            for (int j = 0; j < 4; j++)
                bfr[j] = *(const bf16x8*)&Bs[wn * 64 + j * 16 + r][h * 32 + q * 8];
            #pragma unroll
            for (int i = 0; i < 4; i++)
                #pragma unroll
                for (int j = 0; j < 4; j++)
                    acc[i][j] = __builtin_amdgcn_mfma_f32_16x16x32_bf16(
                        af[i], bfr[j], acc[i][j], 0, 0, 0);
        }
        __syncthreads();
    }

    // cols: wn*64 + j*16 + r over 128 (C_OUT); rows: wm*64 + i*16 + q*4 + p
    #pragma unroll
    for (int j = 0; j < 4; j++) {
        const int ch = wn * 64 + j * 16 + r;
        const float bo = bias[ch];
        #pragma unroll
        for (int i = 0; i < 4; i++) {
            const int mb = m0 + wm * 64 + i * 16 + q * 4;
            #pragma unroll
            for (int p = 0; p < 4; p++) {
                const int m = mb + p;
                if (m < N) Cf[(size_t)m * C_OUT + ch] = acc[i][j][p] + bo;
            }
        }
    }
}

// One wave per point: gather 16 packed rows ([ey|x] halves), all 32 8B loads
// issued up front, pool = (sum ey*x)/(sum ey) per channel, write bf16 feat.
__global__ __launch_bounds__(256)
void gather_k(const u16* __restrict__ packed, const int* __restrict__ nidx,
              u16* __restrict__ featb, int N)
{
    __shared__ int rows[4 * KNBR];
    const int tid = threadIdx.x;
    const int p0 = blockIdx.x * 4;

    if (tid < 4 * KNBR) {
        int n = p0 + (tid >> 4);
        rows[tid] = (n < N) ? nidx[n * KNBR + (tid & 15)] : 0;
    }
    __syncthreads();

    const int w = tid >> 6;       // wave id -> point p0+w
    const int l = tid & 63;       // channels 4l..4l+3
    const int p = p0 + w;
    if (p >= N) return;

    ushort4 eh[KNBR], xh[KNBR];
    #pragma unroll
    for (int k = 0; k < KNBR; k++) {
        const size_t base = (size_t)rows[w * KNBR + k] * 512;
        eh[k] = *(const ushort4*)(packed + base + l * 4);
        xh[k] = *(const ushort4*)(packed + base + 256 + l * 4);
    }

    float d0 = 0.f, d1 = 0.f, d2 = 0.f, d3 = 0.f;
    float u0 = 0.f, u1 = 0.f, u2 = 0.f, u3 = 0.f;
    #pragma unroll
    for (int k = 0; k < KNBR; k++) {
        float e0 = bf2f(eh[k].x), e1 = bf2f(eh[k].y);
        float e2 = bf2f(eh[k].z), e3 = bf2f(eh[k].w);
        d0 += e0; d1 += e1; d2 += e2; d3 += e3;
        u0 = fmaf(e0, bf2f(xh[k].x), u0);
        u1 = fmaf(e1, bf2f(xh[k].y), u1);
        u2 = fmaf(e2, bf2f(xh[k].z), u2);
        u3 = fmaf(e3, bf2f(xh[k].w), u3);
    }
    ushort4 o;
    o.x = f2bf(u0 / d0); o.y = f2bf(u1 / d1);
    o.z = f2bf(u2 / d2); o.w = f2bf(u3 / d3);
    *(ushort4*)(featb + (size_t)p * C2 + l * 4) = o;
}

extern "C" void kernel_launch(void* const* d_in, const int* in_sizes, int n_in,
                              void* d_out, int out_size, void* d_ws, size_t ws_size,
                              hipStream_t stream)
{
    const float* features = (const float*)d_in[0];
    const int*   nidx     = (const int*)d_in[1];
    const float* W1       = (const float*)d_in[2];
    const float* b1       = (const float*)d_in[3];
    const float* gamma    = (const float*)d_in[4];
    const float* beta     = (const float*)d_in[5];
    const float* mean     = (const float*)d_in[6];
    const float* var      = (const float*)d_in[7];
    const float* Ws       = (const float*)d_in[8];
    const float* Wm       = (const float*)d_in[9];
    const float* bm       = (const float*)d_in[10];
    float* out = (float*)d_out;

    const int N = in_sizes[0] / C_IN;   // 50000

    u16* packed = (u16*)d_ws;                      // N x 512 ([ey|x] bf16)
    u16* W1t    = packed + (size_t)N * 512;        // 256 x 128
    u16* Wst    = W1t + 256 * 128;                 // 256 x 256
    u16* Wmt    = Wst + 256 * 256;                 // 128 x 256
    // feat lives in d_out (bf16 N x 256 == 25.6 MB == out buffer exactly).
    // Safe: out_gemm blocks read all their A rows before overwriting them.
    u16* featb = (u16*)d_out;

    prep_k<<<dim3(256, 3), 256, 0, stream>>>(W1, Ws, Wm, W1t, Wst, Wmt);

    const int MT = (N + 127) / 128;   // 391

    // K12 fused: x-half + ey-half of packed
    mlp_k<<<MT, 256, 0, stream>>>(features, W1t, Wst, b1, gamma, beta,
                                  mean, var, packed, N);
    // K3a: gather + pool -> featb (aliases d_out)
    gather_k<<<(N + 3) / 4, 256, 0, stream>>>(packed, nidx, featb, N);
    // K3b: out = featb @ Wm + bm
    out_gemm<<<MT, 256, 0, stream>>>(featb, Wmt, bm, out, N);
}